// Round 3
// baseline (7445.401 us; speedup 1.0000x reference)
//
#include <hip/hip_runtime.h>
#include <math.h>

// ---------------------------------------------------------------------------
// SynchronAutoencoder: 3 stacked synchron-GRU layers, W=512, C=16.
// R6: shrink the recurrent-phase sync group 64 WGs -> 8 WGs (test of the
// congestion hypothesis without R4's serialization mistake).
//  - krr_kernel: 8 WGs x 512. WG g owns columns [64g,64g+64); wave w owns 8
//    columns; lane l: col = 64g+8w+(l&7), k-block kb=l>>3 covering 64 k's
//    (staggered start 8*kb to avoid LDS bank conflicts). All 512x3 rec
//    weights for the lane's column live in 192 VGPRs (loaded once).
//    Per step: every wave independently polls the FULL h (R3's exact
//    agent-scope window poll), decodes into its own LDS row (intra-wave
//    only: lgkmcnt(0) + sched_barrier, no __syncthreads), 192 FMAs,
//    3-shfl reduce over kb, gates in-lane, kb==0 lanes store the wave's 8
//    columns (one 32B store per wave). No per-step barrier anywhere.
//  - krc2_kernel: chain phase (15 steps) unchanged from R3 (64 WGs,
//    bandwidth-parallel kc streaming, part-buffer window protocol); gets y0
//    through the kernel boundary (lout of krr).
// Protocol (harness-proven in R3): h encoded h+base, base 2/8 by (s>>1)&1,
// ping-pong slot s&1; WAR by induction (store of h_{s+1} only after the
// full-window poll of h_s). Chain partials encoded +4/+16 by (ci>>1)&1.
// hbuf+part zeroed per launch (hipMemsetAsync; capture-safe) so first-run
// garbage can't alias into a window.
// ---------------------------------------------------------------------------

#define AGENT __HIP_MEMORY_SCOPE_AGENT

__device__ __forceinline__ float f32_ld(const float* p) {
  return __hip_atomic_load((float*)p, __ATOMIC_RELAXED, AGENT);
}
__device__ __forceinline__ void f32_st(float* p, float v) {
  __hip_atomic_store(p, v, __ATOMIC_RELAXED, AGENT);
}
__device__ __forceinline__ unsigned long long u64_ld(const unsigned long long* p) {
  return __hip_atomic_load((unsigned long long*)p, __ATOMIC_RELAXED, AGENT);
}
__device__ __forceinline__ float loF(unsigned long long u) {
  return __builtin_bit_cast(float, (unsigned)(u & 0xffffffffull));
}
__device__ __forceinline__ float hiF(unsigned long long u) {
  return __builtin_bit_cast(float, (unsigned)(u >> 32));
}
__device__ __forceinline__ float sigm(float x) { return 1.f / (1.f + __expf(-x)); }
__device__ __forceinline__ float tanh_f(float x) {
  float e = __expf(2.f * x);
  return 1.f - 2.f / (e + 1.f);
}

// ---- KA1: chain step-1 hidden state h1[i][u] (parallel, reads kc) ----------
__global__ void ka1_kernel(const float* __restrict__ xin, const float* __restrict__ kc,
                           const float* __restrict__ bc, float* __restrict__ h1) {
  __shared__ float x1s[512];
  __shared__ float red[8][3][32];
  const int tid = threadIdx.x;
  x1s[tid]       = xin[tid * 16 + 1];
  x1s[tid + 256] = xin[(tid + 256) * 16 + 1];
  __syncthreads();
  const int i  = blockIdx.x >> 4;          // chain index 0..14
  const int ub = (blockIdx.x & 15) << 5;   // unit block of 32
  const int s = tid >> 5, c = tid & 31;
  const float* base = kc + (size_t)i * 786432 + ub + c;
  float a0 = 0.f, a1 = 0.f, a2 = 0.f;
  const int kk = s * 64;
  for (int k = kk; k < kk + 64; ++k) {
    const float xv = x1s[k];
    const float* row = base + (size_t)k * 1536;
    a0 = fmaf(xv, row[0],    a0);
    a1 = fmaf(xv, row[512],  a1);
    a2 = fmaf(xv, row[1024], a2);
  }
  red[s][0][c] = a0; red[s][1][c] = a1; red[s][2][c] = a2;
  __syncthreads();
  if (tid < 32) {
    const int u = tid;
    float g0 = 0.f, g1 = 0.f, g2 = 0.f;
    for (int ss = 0; ss < 8; ++ss) { g0 += red[ss][0][u]; g1 += red[ss][1][u]; g2 += red[ss][2][u]; }
    const float* bi = bc + (size_t)i * 3072;
    const float* br = bi + 1536;
    const int cz = ub + u, cr = 512 + ub + u, cn = 1024 + ub + u;
    const float z1  = sigm(g0 + bi[cz] + br[cz]);
    const float r1  = sigm(g1 + bi[cr] + br[cr]);
    const float hh1 = tanh_f(g2 + bi[cn] + r1 * br[cn]);
    h1[i * 512 + ub + u] = (1.f - z1) * hh1;
  }
}

// ---- KA2: gh2[i][col] = h1[i] @ rkc[i] + b_r[col] (parallel, reads rkc) ----
__global__ void ka2_kernel(const float* __restrict__ h1, const float* __restrict__ rkc,
                           const float* __restrict__ bc, float* __restrict__ gh2) {
  __shared__ float hs[512];
  __shared__ float red[4][64];
  const int tid = threadIdx.x;
  const int i  = blockIdx.x / 24;
  const int cb = (blockIdx.x % 24) << 6;
  hs[tid]       = h1[i * 512 + tid];
  hs[tid + 256] = h1[i * 512 + tid + 256];
  __syncthreads();
  const int s = tid >> 6, c = tid & 63;
  const float* base = rkc + (size_t)i * 786432 + cb + c;
  float acc = 0.f;
  const int kk = s * 128;
  for (int k = kk; k < kk + 128; ++k) acc = fmaf(hs[k], base[(size_t)k * 1536], acc);
  red[s][c] = acc;
  __syncthreads();
  if (tid < 64) {
    const float v = red[0][tid] + red[1][tid] + red[2][tid] + red[3][tid];
    gh2[i * 1536 + cb + tid] = v + bc[(size_t)i * 3072 + 1536 + cb + tid];
  }
}

// ---- KRR: recurrent phase, 8 WGs, per-step barrier-free --------------------
__global__ __launch_bounds__(512, 1) void krr_kernel(
    const float* __restrict__ xin, const float* __restrict__ k0,
    const float* __restrict__ rk0, const float* __restrict__ b0,
    float* __restrict__ lout, float* hbuf) {
  __shared__ float x0l[512];
  __shared__ float hsw[8][512];     // per-wave decoded-h row (no cross-wave use)
  const int tid  = threadIdx.x;
  const int g    = blockIdx.x;      // 0..7
  const int wave = tid >> 6, lane = tid & 63;
  const int kb   = lane >> 3;       // k-block 0..7 (64 k's each, staggered)
  const int cl   = g * 64 + wave * 8 + (lane & 7);   // this lane's column

  x0l[tid] = xin[tid * 16];

  // Weights: wreg[p][j] = rk0[k(j)*1536 + p*512 + cl], k(j)=64*kb+((8*kb+j)&63).
  // Stagger (8*kb) makes the per-step LDS reads ~2-way (free) instead of 8-way.
  float wreg[3][64];
#pragma unroll
  for (int p = 0; p < 3; ++p) {
#pragma unroll
    for (int j = 0; j < 64; ++j) {
      const int k = 64 * kb + ((8 * kb + j) & 63);
      wreg[p][j] = rk0[(size_t)k * 1536 + p * 512 + cl];
    }
  }
  const float k0z = k0[cl],        k0r = k0[512 + cl],  k0n  = k0[1024 + cl];
  const float biz = b0[cl],        bir = b0[512 + cl],  bin_ = b0[1024 + cl];
  const float brz = b0[1536 + cl], brr = b0[2048 + cl], brn  = b0[2560 + cl];
  __syncthreads();   // x0l ready (only barrier outside the step loop)

  float hprev = 0.f;
  for (int s = 0; s < 512; ++s) {
    float acc[3][2] = {{0.f, 0.f}, {0.f, 0.f}, {0.f, 0.f}};
    if (s > 0) {
      // ---- poll full h (R3's proven agent-scope window poll) ----
      const float base = ((s >> 1) & 1) ? 8.f : 2.f;
      const unsigned long long* bp =
          (const unsigned long long*)(hbuf + ((s & 1) << 9));
      const unsigned long long* pa = bp + 2 * lane;          // floats 4l..4l+3
      const unsigned long long* pb = bp + 128 + 2 * lane;    // floats 256+4l..
      float hA[8];
      bool ok;
      do {
        const unsigned long long A0 = u64_ld(pa), A1 = u64_ld(pa + 1);
        const unsigned long long B0 = u64_ld(pb), B1 = u64_ld(pb + 1);
        hA[0] = loF(A0); hA[1] = hiF(A0); hA[2] = loF(A1); hA[3] = hiF(A1);
        hA[4] = loF(B0); hA[5] = hiF(B0); hA[6] = loF(B1); hA[7] = hiF(B1);
        ok = true;
#pragma unroll
        for (int j = 0; j < 8; ++j) ok = ok && (__builtin_fabsf(hA[j] - base) < 1.25f);
      } while (!__all(ok));
#pragma unroll
      for (int j = 0; j < 8; ++j) hA[j] -= base;
      // ---- intra-wave redistribution via own LDS row (no barrier) ----
      float* hw = &hsw[wave][0];
      *(float4*)&hw[4 * lane]       = make_float4(hA[0], hA[1], hA[2], hA[3]);
      *(float4*)&hw[256 + 4 * lane] = make_float4(hA[4], hA[5], hA[6], hA[7]);
      asm volatile("s_waitcnt lgkmcnt(0)" ::: "memory");
      __builtin_amdgcn_sched_barrier(0);   // rule-18: pin reads after the wait
      const float* hb = &hsw[wave][64 * kb];
#pragma unroll
      for (int jc = 0; jc < 16; ++jc) {
        const int off = (8 * kb + 4 * jc) & 63;   // staggered, 16B-aligned
        const float4 hv = *(const float4*)(hb + off);
        const int q = jc & 1;                      // 2 chains/gate for ILP
        acc[0][q] = fmaf(hv.x, wreg[0][4 * jc + 0], acc[0][q]);
        acc[0][q] = fmaf(hv.y, wreg[0][4 * jc + 1], acc[0][q]);
        acc[0][q] = fmaf(hv.z, wreg[0][4 * jc + 2], acc[0][q]);
        acc[0][q] = fmaf(hv.w, wreg[0][4 * jc + 3], acc[0][q]);
        acc[1][q] = fmaf(hv.x, wreg[1][4 * jc + 0], acc[1][q]);
        acc[1][q] = fmaf(hv.y, wreg[1][4 * jc + 1], acc[1][q]);
        acc[1][q] = fmaf(hv.z, wreg[1][4 * jc + 2], acc[1][q]);
        acc[1][q] = fmaf(hv.w, wreg[1][4 * jc + 3], acc[1][q]);
        acc[2][q] = fmaf(hv.x, wreg[2][4 * jc + 0], acc[2][q]);
        acc[2][q] = fmaf(hv.y, wreg[2][4 * jc + 1], acc[2][q]);
        acc[2][q] = fmaf(hv.z, wreg[2][4 * jc + 2], acc[2][q]);
        acc[2][q] = fmaf(hv.w, wreg[2][4 * jc + 3], acc[2][q]);
      }
    }
    // ---- reduce over kb (lanes with same l&7 share a column) ----
    float d0 = acc[0][0] + acc[0][1];
    float d1 = acc[1][0] + acc[1][1];
    float d2 = acc[2][0] + acc[2][1];
    d0 += __shfl_xor(d0, 8); d0 += __shfl_xor(d0, 16); d0 += __shfl_xor(d0, 32);
    d1 += __shfl_xor(d1, 8); d1 += __shfl_xor(d1, 16); d1 += __shfl_xor(d1, 32);
    d2 += __shfl_xor(d2, 8); d2 += __shfl_xor(d2, 16); d2 += __shfl_xor(d2, 32);
    // ---- gates (redundant across kb replicas; identical results) ----
    const float xt = x0l[s];
    const float z  = sigm(fmaf(xt, k0z, biz) + d0 + brz);
    const float r  = sigm(fmaf(xt, k0r, bir) + d1 + brr);
    const float hh = tanh_f(fmaf(xt, k0n, bin_) + r * (d2 + brn));
    const float hnew = z * hprev + (1.f - z) * hh;
    hprev = hnew;
    if (kb == 0) {                       // lanes 0..7: one 32B store per wave
      if (s < 511) {
        const float nb = (((s + 1) >> 1) & 1) ? 8.f : 2.f;
        f32_st(&hbuf[(((s + 1) & 1) << 9) + cl], hnew + nb);
      } else {
        lout[cl] = hnew;                 // y0 (visible to krc2 at kernel boundary)
      }
    }
  }
}

// ---- KRC2: chain phase, 64 WGs (R3's proven structure) ---------------------
__global__ __launch_bounds__(512, 1) void krc2_kernel(
    const float* __restrict__ kc, const float* __restrict__ bc,
    const float* __restrict__ h1, const float* __restrict__ gh2,
    const float* __restrict__ y0, float* __restrict__ lout, float* part) {
  __shared__ float ccon[15 * 56];   // per ci: bi_d[24], g2_d[24], h1v[8]
  __shared__ float dots[24];
  __shared__ float yl[8];
  const int tid  = threadIdx.x;
  const int g    = blockIdx.x;
  const int wave = tid >> 6, lane = tid & 63;
  const int col8 = g * 8;

  for (int idx = tid; idx < 15 * 56; idx += 512) {
    const int ci = idx / 56, r = idx - ci * 56;
    float v;
    if (r < 24)      v = bc[(size_t)ci * 3072 + (r >> 3) * 512 + col8 + (r & 7)];
    else if (r < 48) v = gh2[ci * 1536 + ((r - 24) >> 3) * 512 + col8 + ((r - 24) & 7)];
    else             v = h1[ci * 512 + col8 + (r - 48)];
    ccon[idx] = v;
  }
  if (tid < 8) yl[tid] = y0[col8 + tid];
  const int col = col8 + tid;   // valid for tid<8
  __syncthreads();

  for (int ci = 0; ci < 15; ++ci) {
    float y[8];
#pragma unroll
    for (int j = 0; j < 8; ++j) y[j] = yl[j];
    const float* kbase = kc + (size_t)ci * 786432 + (size_t)col8 * 1536 + tid;
    float a0 = 0.f, a1 = 0.f, a2 = 0.f;
#pragma unroll
    for (int j = 0; j < 8; ++j) {
      const float* row = kbase + (size_t)j * 1536;
      a0 = fmaf(y[j], row[0],    a0);
      a1 = fmaf(y[j], row[512],  a1);
      a2 = fmaf(y[j], row[1024], a2);
    }
    const float pb = ((ci >> 1) & 1) ? 16.f : 4.f;   // |partial| <= ~1.5 << 3
    float* pbuf = part + (size_t)(ci & 1) * (1536 * 64);
    f32_st(&pbuf[(size_t)tid * 64 + g],          a0 + pb);
    f32_st(&pbuf[(size_t)(tid + 512) * 64 + g],  a1 + pb);
    f32_st(&pbuf[(size_t)(tid + 1024) * 64 + g], a2 + pb);

    const float* r0 = &pbuf[(size_t)(col8 + wave) * 64 + lane];
    const float* r1 = &pbuf[(size_t)(512 + col8 + wave) * 64 + lane];
    const float* r2 = &pbuf[(size_t)(1024 + col8 + wave) * 64 + lane];
    float v0, v1, v2;
    bool ok;
    do {
      v0 = f32_ld(r0); v1 = f32_ld(r1); v2 = f32_ld(r2);
      ok = (__builtin_fabsf(v0 - pb) < 3.f) &&
           (__builtin_fabsf(v1 - pb) < 3.f) &&
           (__builtin_fabsf(v2 - pb) < 3.f);
    } while (!__all(ok));
    v0 -= pb; v1 -= pb; v2 -= pb;
    v0 += __shfl_xor(v0, 1);  v0 += __shfl_xor(v0, 2);  v0 += __shfl_xor(v0, 4);
    v0 += __shfl_xor(v0, 8);  v0 += __shfl_xor(v0, 16); v0 += __shfl_xor(v0, 32);
    v1 += __shfl_xor(v1, 1);  v1 += __shfl_xor(v1, 2);  v1 += __shfl_xor(v1, 4);
    v1 += __shfl_xor(v1, 8);  v1 += __shfl_xor(v1, 16); v1 += __shfl_xor(v1, 32);
    v2 += __shfl_xor(v2, 1);  v2 += __shfl_xor(v2, 2);  v2 += __shfl_xor(v2, 4);
    v2 += __shfl_xor(v2, 8);  v2 += __shfl_xor(v2, 16); v2 += __shfl_xor(v2, 32);
    if (lane == 0) { dots[wave] = v0; dots[8 + wave] = v1; dots[16 + wave] = v2; }
    __syncthreads();
    if (tid < 8) {
      const float* cc = &ccon[ci * 56];
      const float dz = dots[tid], dr = dots[8 + tid], dn = dots[16 + tid];
      const float z  = sigm(dz + cc[tid]      + cc[24 + tid]);
      const float r  = sigm(dr + cc[8 + tid]  + cc[32 + tid]);
      const float hh = tanh_f(dn + cc[16 + tid] + r * cc[40 + tid]);
      const float hnew = z * cc[48 + tid] + (1.f - z) * hh;
      lout[(ci + 1) * 512 + col] = hnew;
      yl[tid] = hnew;
    }
    __syncthreads();   // yl visible for next step's partials
  }
}

// ---------------------------------------------------------------------------
// d_ws layout (floats):
//   hbuf:  3 * 1024                      @ 0
//   part:  3 * 196608                    @ 3072    (ends 592896)
//   h1:    15*512                        @ 592896
//   gh2:   15*1536                       @ 600576
//   lay1:  8192                          @ 623616
//   lay2:  8192                          @ 631808   (total 640000 fl = 2.56 MB)
// hbuf+part ([0,592896)) zeroed per launch: first-run garbage can't alias
// into a poll window (0 is out of every window).
// ---------------------------------------------------------------------------
extern "C" void kernel_launch(void* const* d_in, const int* in_sizes, int n_in,
                              void* d_out, int out_size, void* d_ws, size_t ws_size,
                              hipStream_t stream) {
  (void)in_sizes; (void)n_in; (void)out_size; (void)ws_size;
  const float* x = (const float*)d_in[0];
  float* F    = (float*)d_ws;
  float* hbuf = F;                 // 3*1024
  float* part = F + 3072;          // 3*196608
  float* h1   = F + 592896;        // 7680
  float* gh2  = F + 600576;        // 23040
  float* lay1 = F + 623616;        // 8192
  float* lay2 = F + 631808;        // 8192
  float* outf = (float*)d_out;

  hipMemsetAsync(F, 0, 592896 * sizeof(float), stream);

  const float* lin = x;
  float* louts[3] = {lay1, lay2, outf};
  for (int l = 0; l < 3; ++l) {
    const float* k0  = (const float*)d_in[1 + 6 * l + 0];
    const float* rk0 = (const float*)d_in[1 + 6 * l + 1];
    const float* b0  = (const float*)d_in[1 + 6 * l + 2];
    const float* kc  = (const float*)d_in[1 + 6 * l + 3];
    const float* rkc = (const float*)d_in[1 + 6 * l + 4];
    const float* bc  = (const float*)d_in[1 + 6 * l + 5];
    ka1_kernel<<<240, 256, 0, stream>>>(lin, kc, bc, h1);
    ka2_kernel<<<360, 256, 0, stream>>>(h1, rkc, bc, gh2);
    krr_kernel<<<8, 512, 0, stream>>>(lin, k0, rk0, b0, louts[l],
                                      hbuf + l * 1024);
    krc2_kernel<<<64, 512, 0, stream>>>(kc, bc, h1, gh2, louts[l], louts[l],
                                        part + (size_t)l * 196608);
    lin = louts[l];
  }
}

// Round 4
// 5235.798 us; speedup vs baseline: 1.4220x; 1.4220x over previous
//
#include <hip/hip_runtime.h>
#include <math.h>

// ---------------------------------------------------------------------------
// SynchronAutoencoder: 3 stacked synchron-GRU layers, W=512, C=16.
// R7 = R3 (proven 1475us/layer) + 2-deep software-pipelined polls.
// Poll loops rotate two load-sets so one set is always in flight while the
// other is checked: sampling period ~RT/2 instead of ~RT. Compiler's
// per-use vmcnt tracking provides the overlap; worst case it waits vmcnt(0)
// and degrades to exactly R3. Window-check correctness is per-float, so any
// old/new mix across a set is safe (same argument as R3).
//
// Design recap: barrier-free persistent kernel. Producers publish h encoded
// as h+base (base alternates 2/8 by (step>>1)&1) into a ping-pong buffer;
// consumers poll the exact floats they need until in-window. Chain steps use
// row-slice partials (own y in registers, kc streamed coalesced) encoded
// with bases 4/16. WAR safety by induction through each WG's __syncthreads.
// Store side stays R3: one 32B store per WG per step (R4 showed scattered
// 4B stores cost +0.6us/step); funnel via dots[]+barrier+tid<8 retained.
// ---------------------------------------------------------------------------

#define AGENT __HIP_MEMORY_SCOPE_AGENT
#define NWG   64

__device__ __forceinline__ float f32_ld(const float* p) {
  return __hip_atomic_load((float*)p, __ATOMIC_RELAXED, AGENT);
}
__device__ __forceinline__ void f32_st(float* p, float v) {
  __hip_atomic_store(p, v, __ATOMIC_RELAXED, AGENT);
}
__device__ __forceinline__ unsigned long long u64_ld(const unsigned long long* p) {
  return __hip_atomic_load((unsigned long long*)p, __ATOMIC_RELAXED, AGENT);
}
__device__ __forceinline__ float loF(unsigned long long u) {
  return __builtin_bit_cast(float, (unsigned)(u & 0xffffffffull));
}
__device__ __forceinline__ float hiF(unsigned long long u) {
  return __builtin_bit_cast(float, (unsigned)(u >> 32));
}
__device__ __forceinline__ float sigm(float x) { return 1.f / (1.f + __expf(-x)); }
__device__ __forceinline__ float tanh_f(float x) {
  float e = __expf(2.f * x);
  return 1.f - 2.f / (e + 1.f);
}

// ---- KA1: chain step-1 hidden state h1[i][u] (parallel, reads kc) ----------
__global__ void ka1_kernel(const float* __restrict__ xin, const float* __restrict__ kc,
                           const float* __restrict__ bc, float* __restrict__ h1) {
  __shared__ float x1s[512];
  __shared__ float red[8][3][32];
  const int tid = threadIdx.x;
  x1s[tid]       = xin[tid * 16 + 1];
  x1s[tid + 256] = xin[(tid + 256) * 16 + 1];
  __syncthreads();
  const int i  = blockIdx.x >> 4;          // chain index 0..14
  const int ub = (blockIdx.x & 15) << 5;   // unit block of 32
  const int s = tid >> 5, c = tid & 31;
  const float* base = kc + (size_t)i * 786432 + ub + c;
  float a0 = 0.f, a1 = 0.f, a2 = 0.f;
  const int kk = s * 64;
  for (int k = kk; k < kk + 64; ++k) {
    const float xv = x1s[k];
    const float* row = base + (size_t)k * 1536;
    a0 = fmaf(xv, row[0],    a0);
    a1 = fmaf(xv, row[512],  a1);
    a2 = fmaf(xv, row[1024], a2);
  }
  red[s][0][c] = a0; red[s][1][c] = a1; red[s][2][c] = a2;
  __syncthreads();
  if (tid < 32) {
    const int u = tid;
    float g0 = 0.f, g1 = 0.f, g2 = 0.f;
    for (int ss = 0; ss < 8; ++ss) { g0 += red[ss][0][u]; g1 += red[ss][1][u]; g2 += red[ss][2][u]; }
    const float* bi = bc + (size_t)i * 3072;
    const float* br = bi + 1536;
    const int cz = ub + u, cr = 512 + ub + u, cn = 1024 + ub + u;
    const float z1  = sigm(g0 + bi[cz] + br[cz]);
    const float r1  = sigm(g1 + bi[cr] + br[cr]);
    const float hh1 = tanh_f(g2 + bi[cn] + r1 * br[cn]);
    h1[i * 512 + ub + u] = (1.f - z1) * hh1;
  }
}

// ---- KA2: gh2[i][col] = h1[i] @ rkc[i] + b_r[col] (parallel, reads rkc) ----
__global__ void ka2_kernel(const float* __restrict__ h1, const float* __restrict__ rkc,
                           const float* __restrict__ bc, float* __restrict__ gh2) {
  __shared__ float hs[512];
  __shared__ float red[4][64];
  const int tid = threadIdx.x;
  const int i  = blockIdx.x / 24;
  const int cb = (blockIdx.x % 24) << 6;
  hs[tid]       = h1[i * 512 + tid];
  hs[tid + 256] = h1[i * 512 + tid + 256];
  __syncthreads();
  const int s = tid >> 6, c = tid & 63;
  const float* base = rkc + (size_t)i * 786432 + cb + c;
  float acc = 0.f;
  const int kk = s * 128;
  for (int k = kk; k < kk + 128; ++k) acc = fmaf(hs[k], base[(size_t)k * 1536], acc);
  red[s][c] = acc;
  __syncthreads();
  if (tid < 64) {
    const float v = red[0][tid] + red[1][tid] + red[2][tid] + red[3][tid];
    gh2[i * 1536 + cb + tid] = v + bc[(size_t)i * 3072 + 1536 + cb + tid];
  }
}

// ---- KRC: persistent, barrier-free recurrent kernel ------------------------
// WG g owns units [8g, 8g+8). Rec dot for (gate p, unit wave) computed by
// wave `wave`, pass p; weights live in 24 registers/thread (hoisted).
__global__ __launch_bounds__(512, 1) void krc_kernel(
    const float* __restrict__ xin, const float* __restrict__ k0,
    const float* __restrict__ rk0, const float* __restrict__ b0,
    const float* __restrict__ kc, const float* __restrict__ bc,
    const float* __restrict__ h1, const float* __restrict__ gh2,
    float* __restrict__ lout, float* hbuf, float* part) {
  __shared__ float x0l[512];
  __shared__ float ccon[15 * 56];   // per ci: bi_d[24], g2_d[24], h1v[8]
  __shared__ float dots[24];
  __shared__ float yl[8];
  const int tid  = threadIdx.x;
  const int g    = blockIdx.x;
  const int wave = tid >> 6, lane = tid & 63;
  const int col8 = g * 8;

  x0l[tid] = xin[tid * 16];
  for (int idx = tid; idx < 15 * 56; idx += 512) {
    const int ci = idx / 56, r = idx - ci * 56;
    float v;
    if (r < 24)      v = bc[(size_t)ci * 3072 + (r >> 3) * 512 + col8 + (r & 7)];
    else if (r < 48) v = gh2[ci * 1536 + ((r - 24) >> 3) * 512 + col8 + ((r - 24) & 7)];
    else             v = h1[ci * 512 + col8 + (r - 48)];
    ccon[idx] = v;
  }

  // Recurrent weight fragments (constant over all 512 steps): w[p][j] covers
  // k in {4*lane+j} u {256+4*lane+j} for column p*512 + col8 + wave.
  float w[3][8];
  {
    const int c0 = col8 + wave;
#pragma unroll
    for (int p = 0; p < 3; ++p) {
      const float* cp = rk0 + p * 512 + c0;
#pragma unroll
      for (int j = 0; j < 4; ++j) {
        w[p][j]     = cp[(size_t)(4 * lane + j) * 1536];
        w[p][4 + j] = cp[(size_t)(256 + 4 * lane + j) * 1536];
      }
    }
  }
  float k0z = 0.f, k0r = 0.f, k0n = 0.f, biz = 0.f, bir = 0.f, bin_ = 0.f;
  float brz = 0.f, brr = 0.f, brn = 0.f;
  const int col = col8 + tid;   // valid for tid<8
  if (tid < 8) {
    k0z = k0[col];        k0r = k0[512 + col];  k0n = k0[1024 + col];
    biz = b0[col];        bir = b0[512 + col];  bin_ = b0[1024 + col];
    brz = b0[1536 + col]; brr = b0[2048 + col]; brn = b0[2560 + col];
  }
  __syncthreads();

  // ---------------- recurrent phase: 512 steps ----------------
  float hprev = 0.f;                 // own-unit h, lanes 0-7 of wave 0
  for (int s = 0; s < 512; ++s) {
    float hA[8];
    if (s == 0) {
#pragma unroll
      for (int j = 0; j < 8; ++j) hA[j] = 0.f;
    } else {
      const float base = ((s >> 1) & 1) ? 8.f : 2.f;
      const unsigned long long* bp =
          (const unsigned long long*)(hbuf + ((s & 1) << 9));
      const unsigned long long* pa = bp + 2 * lane;          // floats 4l..4l+3
      const unsigned long long* pb = bp + 128 + 2 * lane;    // floats 256+4l..
      // 2-deep pipelined poll: set X in flight while set Y is checked.
      unsigned long long A0 = u64_ld(pa), A1 = u64_ld(pa + 1);
      unsigned long long A2 = u64_ld(pb), A3 = u64_ld(pb + 1);
      for (;;) {
        // issue set B
        const unsigned long long B0 = u64_ld(pa), B1 = u64_ld(pa + 1);
        const unsigned long long B2 = u64_ld(pb), B3 = u64_ld(pb + 1);
        // check set A (compiler waits only on A's loads)
        hA[0] = loF(A0); hA[1] = hiF(A0); hA[2] = loF(A1); hA[3] = hiF(A1);
        hA[4] = loF(A2); hA[5] = hiF(A2); hA[6] = loF(A3); hA[7] = hiF(A3);
        bool ok = true;
#pragma unroll
        for (int j = 0; j < 8; ++j) ok = ok && (__builtin_fabsf(hA[j] - base) < 1.25f);
        if (__all(ok)) break;
        // re-issue set A
        A0 = u64_ld(pa); A1 = u64_ld(pa + 1); A2 = u64_ld(pb); A3 = u64_ld(pb + 1);
        // check set B
        hA[0] = loF(B0); hA[1] = hiF(B0); hA[2] = loF(B1); hA[3] = hiF(B1);
        hA[4] = loF(B2); hA[5] = hiF(B2); hA[6] = loF(B3); hA[7] = hiF(B3);
        ok = true;
#pragma unroll
        for (int j = 0; j < 8; ++j) ok = ok && (__builtin_fabsf(hA[j] - base) < 1.25f);
        if (__all(ok)) break;
      }
#pragma unroll
      for (int j = 0; j < 8; ++j) hA[j] -= base;
    }
#pragma unroll
    for (int p = 0; p < 3; ++p) {
      float v = 0.f;
#pragma unroll
      for (int j = 0; j < 8; ++j) v = fmaf(hA[j], w[p][j], v);
      v += __shfl_xor(v, 1);  v += __shfl_xor(v, 2);  v += __shfl_xor(v, 4);
      v += __shfl_xor(v, 8);  v += __shfl_xor(v, 16); v += __shfl_xor(v, 32);
      if (lane == 0) dots[p * 8 + wave] = v;
    }
    __syncthreads();
    if (tid < 8) {
      const float dz = dots[tid], dr = dots[8 + tid], dn = dots[16 + tid];
      const float xt = x0l[s];
      const float z  = sigm(fmaf(xt, k0z, biz) + dz + brz);
      const float r  = sigm(fmaf(xt, k0r, bir) + dr + brr);
      const float hh = tanh_f(fmaf(xt, k0n, bin_) + r * (dn + brn));
      const float hnew = z * hprev + (1.f - z) * hh;
      hprev = hnew;
      if (s < 511) {
        const float nb = (((s + 1) >> 1) & 1) ? 8.f : 2.f;
        f32_st(&hbuf[(((s + 1) & 1) << 9) + col], hnew + nb);
      } else {
        lout[col] = hnew;    // y0
        yl[tid]   = hnew;
      }
    }
  }
  __syncthreads();   // yl visible to whole WG

  // ---------------- chain phase: 15 steps ----------------
  // Row-slice partials: WG g uses ONLY its own y slice (yl) and its 8 kc
  // rows (coalesced). part[c][64] per column; reduce is coalesced 256B rows.
  for (int ci = 0; ci < 15; ++ci) {
    float y[8];
#pragma unroll
    for (int j = 0; j < 8; ++j) y[j] = yl[j];
    const float* kbase = kc + (size_t)ci * 786432 + (size_t)col8 * 1536 + tid;
    float a0 = 0.f, a1 = 0.f, a2 = 0.f;
#pragma unroll
    for (int j = 0; j < 8; ++j) {
      const float* row = kbase + (size_t)j * 1536;
      a0 = fmaf(y[j], row[0],    a0);
      a1 = fmaf(y[j], row[512],  a1);
      a2 = fmaf(y[j], row[1024], a2);
    }
    const float pb = ((ci >> 1) & 1) ? 16.f : 4.f;   // |partial| <= ~1.5 << 3
    float* pbuf = part + (size_t)(ci & 1) * (1536 * 64);
    f32_st(&pbuf[(size_t)tid * 64 + g],          a0 + pb);
    f32_st(&pbuf[(size_t)(tid + 512) * 64 + g],  a1 + pb);
    f32_st(&pbuf[(size_t)(tid + 1024) * 64 + g], a2 + pb);

    const float* r0 = &pbuf[(size_t)(col8 + wave) * 64 + lane];
    const float* r1 = &pbuf[(size_t)(512 + col8 + wave) * 64 + lane];
    const float* r2 = &pbuf[(size_t)(1024 + col8 + wave) * 64 + lane];
    // 2-deep pipelined poll (same pattern as recurrent phase).
    float v0, v1, v2;
    float A0 = f32_ld(r0), A1 = f32_ld(r1), A2 = f32_ld(r2);
    for (;;) {
      const float B0 = f32_ld(r0), B1 = f32_ld(r1), B2 = f32_ld(r2);
      bool ok = (__builtin_fabsf(A0 - pb) < 3.f) &&
                (__builtin_fabsf(A1 - pb) < 3.f) &&
                (__builtin_fabsf(A2 - pb) < 3.f);
      if (__all(ok)) { v0 = A0; v1 = A1; v2 = A2; break; }
      A0 = f32_ld(r0); A1 = f32_ld(r1); A2 = f32_ld(r2);
      ok = (__builtin_fabsf(B0 - pb) < 3.f) &&
           (__builtin_fabsf(B1 - pb) < 3.f) &&
           (__builtin_fabsf(B2 - pb) < 3.f);
      if (__all(ok)) { v0 = B0; v1 = B1; v2 = B2; break; }
    }
    v0 -= pb; v1 -= pb; v2 -= pb;
    v0 += __shfl_xor(v0, 1);  v0 += __shfl_xor(v0, 2);  v0 += __shfl_xor(v0, 4);
    v0 += __shfl_xor(v0, 8);  v0 += __shfl_xor(v0, 16); v0 += __shfl_xor(v0, 32);
    v1 += __shfl_xor(v1, 1);  v1 += __shfl_xor(v1, 2);  v1 += __shfl_xor(v1, 4);
    v1 += __shfl_xor(v1, 8);  v1 += __shfl_xor(v1, 16); v1 += __shfl_xor(v1, 32);
    v2 += __shfl_xor(v2, 1);  v2 += __shfl_xor(v2, 2);  v2 += __shfl_xor(v2, 4);
    v2 += __shfl_xor(v2, 8);  v2 += __shfl_xor(v2, 16); v2 += __shfl_xor(v2, 32);
    if (lane == 0) { dots[wave] = v0; dots[8 + wave] = v1; dots[16 + wave] = v2; }
    __syncthreads();
    if (tid < 8) {
      const float* cc = &ccon[ci * 56];
      const float dz = dots[tid], dr = dots[8 + tid], dn = dots[16 + tid];
      const float z  = sigm(dz + cc[tid]      + cc[24 + tid]);
      const float r  = sigm(dr + cc[8 + tid]  + cc[32 + tid]);
      const float hh = tanh_f(dn + cc[16 + tid] + r * cc[40 + tid]);
      const float hnew = z * cc[48 + tid] + (1.f - z) * hh;
      lout[(ci + 1) * 512 + col] = hnew;
      yl[tid] = hnew;
    }
    __syncthreads();   // yl visible for next step's partials
  }
}

// ---------------------------------------------------------------------------
// d_ws layout (floats, per-layer regions to avoid cross-layer stale-valid
// aliasing of the encoded buffers):
//   hbuf:  3 * 1024                      @ 0
//   part:  3 * 2*1536*64 = 3*196608      @ 3072
//   h1:    15*512                        @ 592896
//   gh2:   15*1536                       @ 600576
//   lay1:  8192                          @ 623616
//   lay2:  8192                          @ 631808    (total ~2.56 MB)
// ---------------------------------------------------------------------------
extern "C" void kernel_launch(void* const* d_in, const int* in_sizes, int n_in,
                              void* d_out, int out_size, void* d_ws, size_t ws_size,
                              hipStream_t stream) {
  (void)in_sizes; (void)n_in; (void)out_size; (void)ws_size;
  const float* x = (const float*)d_in[0];
  float* F    = (float*)d_ws;
  float* hbuf = F;                 // 3*1024
  float* part = F + 3072;          // 3*196608
  float* h1   = F + 592896;        // 7680
  float* gh2  = F + 600576;        // 23040
  float* lay1 = F + 623616;        // 8192
  float* lay2 = F + 631808;        // 8192
  float* outf = (float*)d_out;

  const float* lin = x;
  float* louts[3] = {lay1, lay2, outf};
  for (int l = 0; l < 3; ++l) {
    const float* k0  = (const float*)d_in[1 + 6 * l + 0];
    const float* rk0 = (const float*)d_in[1 + 6 * l + 1];
    const float* b0  = (const float*)d_in[1 + 6 * l + 2];
    const float* kc  = (const float*)d_in[1 + 6 * l + 3];
    const float* rkc = (const float*)d_in[1 + 6 * l + 4];
    const float* bc  = (const float*)d_in[1 + 6 * l + 5];
    ka1_kernel<<<240, 256, 0, stream>>>(lin, kc, bc, h1);
    ka2_kernel<<<360, 256, 0, stream>>>(h1, rkc, bc, gh2);
    krc_kernel<<<NWG, 512, 0, stream>>>(lin, k0, rk0, b0, kc, bc, h1, gh2,
                                        louts[l], hbuf + l * 1024,
                                        part + (size_t)l * 393216);
    lin = louts[l];
  }
}

// Round 5
// 3361.015 us; speedup vs baseline: 2.2152x; 1.5578x over previous
//
#include <hip/hip_runtime.h>
#include <math.h>

// ---------------------------------------------------------------------------
// SynchronAutoencoder: 3 stacked synchron-GRU layers, W=512, C=16.
// R8: low-pressure recurrent kernel (krr, 16 WGs) + proven chain kernel.
//  - krr: WG g owns cols [32g,32g+32). Wave w polls ONLY h[64w..64w+64)
//    (1 atomic float per lane; ~16 waves/line chip-wide vs 512 in R3).
//    Lane l: col c=32g+(l&31), k in [64w+32*(l>>5), +32), weights in 96
//    VGPRs (static indexing only -> no spill; R6's 192-reg array spilled).
//    h redistribution intra-wave via 32 __shfl (no LDS, no barrier).
//    Cross-wave reduce: red[s&1][wave][gate][col] + ONE __syncthreads/step;
//    wave0 lanes0-31 finish gates, store ONE coalesced 128B line per WG
//    (R4: scattered stores cost +0.6us/step).
//  - WAR safety (one barrier/step): red[] is parity-double-buffered; writes
//    to red[par] for step s+2 are gated by poll(h_{s+2}) which transitively
//    requires every WG's wave0 to have read red[par] for step s (chain goes
//    through each producer WG's barrier + store). Same induction covers the
//    hbuf ping-pong slots. Deadlock-free by induction from s=0 (no poll).
//  - Windows: h encoded h+base, base 2/8 by (s>>1)&1, slot s&1; chain
//    partials +4/+16 by (ci>>1)&1. hbuf+part memset to 0 per launch (0 is
//    outside every window -> no first-run/cross-replay stale-valid aliasing).
//  - ka1/ka2/krc2 verbatim from R6's passing run.
// ---------------------------------------------------------------------------

#define AGENT __HIP_MEMORY_SCOPE_AGENT
#define NWG   64
#define NWGR  16

__device__ __forceinline__ float f32_ld(const float* p) {
  return __hip_atomic_load((float*)p, __ATOMIC_RELAXED, AGENT);
}
__device__ __forceinline__ void f32_st(float* p, float v) {
  __hip_atomic_store(p, v, __ATOMIC_RELAXED, AGENT);
}
__device__ __forceinline__ float sigm(float x) { return 1.f / (1.f + __expf(-x)); }
__device__ __forceinline__ float tanh_f(float x) {
  float e = __expf(2.f * x);
  return 1.f - 2.f / (e + 1.f);
}

// ---- KA1: chain step-1 hidden state h1[i][u] (parallel, reads kc) ----------
__global__ void ka1_kernel(const float* __restrict__ xin, const float* __restrict__ kc,
                           const float* __restrict__ bc, float* __restrict__ h1) {
  __shared__ float x1s[512];
  __shared__ float red[8][3][32];
  const int tid = threadIdx.x;
  x1s[tid]       = xin[tid * 16 + 1];
  x1s[tid + 256] = xin[(tid + 256) * 16 + 1];
  __syncthreads();
  const int i  = blockIdx.x >> 4;          // chain index 0..14
  const int ub = (blockIdx.x & 15) << 5;   // unit block of 32
  const int s = tid >> 5, c = tid & 31;
  const float* base = kc + (size_t)i * 786432 + ub + c;
  float a0 = 0.f, a1 = 0.f, a2 = 0.f;
  const int kk = s * 64;
  for (int k = kk; k < kk + 64; ++k) {
    const float xv = x1s[k];
    const float* row = base + (size_t)k * 1536;
    a0 = fmaf(xv, row[0],    a0);
    a1 = fmaf(xv, row[512],  a1);
    a2 = fmaf(xv, row[1024], a2);
  }
  red[s][0][c] = a0; red[s][1][c] = a1; red[s][2][c] = a2;
  __syncthreads();
  if (tid < 32) {
    const int u = tid;
    float g0 = 0.f, g1 = 0.f, g2 = 0.f;
    for (int ss = 0; ss < 8; ++ss) { g0 += red[ss][0][u]; g1 += red[ss][1][u]; g2 += red[ss][2][u]; }
    const float* bi = bc + (size_t)i * 3072;
    const float* br = bi + 1536;
    const int cz = ub + u, cr = 512 + ub + u, cn = 1024 + ub + u;
    const float z1  = sigm(g0 + bi[cz] + br[cz]);
    const float r1  = sigm(g1 + bi[cr] + br[cr]);
    const float hh1 = tanh_f(g2 + bi[cn] + r1 * br[cn]);
    h1[i * 512 + ub + u] = (1.f - z1) * hh1;
  }
}

// ---- KA2: gh2[i][col] = h1[i] @ rkc[i] + b_r[col] (parallel, reads rkc) ----
__global__ void ka2_kernel(const float* __restrict__ h1, const float* __restrict__ rkc,
                           const float* __restrict__ bc, float* __restrict__ gh2) {
  __shared__ float hs[512];
  __shared__ float red[4][64];
  const int tid = threadIdx.x;
  const int i  = blockIdx.x / 24;
  const int cb = (blockIdx.x % 24) << 6;
  hs[tid]       = h1[i * 512 + tid];
  hs[tid + 256] = h1[i * 512 + tid + 256];
  __syncthreads();
  const int s = tid >> 6, c = tid & 63;
  const float* base = rkc + (size_t)i * 786432 + cb + c;
  float acc = 0.f;
  const int kk = s * 128;
  for (int k = kk; k < kk + 128; ++k) acc = fmaf(hs[k], base[(size_t)k * 1536], acc);
  red[s][c] = acc;
  __syncthreads();
  if (tid < 64) {
    const float v = red[0][tid] + red[1][tid] + red[2][tid] + red[3][tid];
    gh2[i * 1536 + cb + tid] = v + bc[(size_t)i * 3072 + 1536 + cb + tid];
  }
}

// ---- KRR: recurrent phase, 16 WGs, slice-polls, one barrier/step -----------
__global__ __launch_bounds__(512, 1) void krr_kernel(
    const float* __restrict__ xin, const float* __restrict__ k0,
    const float* __restrict__ rk0, const float* __restrict__ b0,
    float* __restrict__ lout, float* hbuf) {
  __shared__ float x0l[512];
  __shared__ float red[2][8][3][32];   // [s&1][wave][gate][col-in-WG]
  const int tid  = threadIdx.x;
  const int g    = blockIdx.x;         // 0..15
  const int wave = tid >> 6, lane = tid & 63;

  x0l[tid] = xin[tid * 16];

  // Weights: lane covers col c = 32g+(lane&31), k in [K0, K0+32),
  // K0 = 64*wave + 32*(lane>>5). 96 VGPRs, all indexing compile-time static.
  const int c  = 32 * g + (lane & 31);
  const int K0 = 64 * wave + 32 * (lane >> 5);
  float w3[3][32];
  {
    const float* wb = rk0 + (size_t)K0 * 1536 + c;
#pragma unroll
    for (int p = 0; p < 3; ++p)
#pragma unroll
      for (int j = 0; j < 32; ++j)
        w3[p][j] = wb[(size_t)j * 1536 + p * 512];
  }
  // Gate scalars for the finishing lanes (wave 0, lanes 0..31).
  float k0z = 0.f, k0r = 0.f, k0n = 0.f, biz = 0.f, bir = 0.f, bin_ = 0.f;
  float brz = 0.f, brr = 0.f, brn = 0.f;
  if (tid < 32) {
    const int cc = 32 * g + tid;
    k0z = k0[cc];        k0r = k0[512 + cc];  k0n  = k0[1024 + cc];
    biz = b0[cc];        bir = b0[512 + cc];  bin_ = b0[1024 + cc];
    brz = b0[1536 + cc]; brr = b0[2048 + cc]; brn  = b0[2560 + cc];
  }
  __syncthreads();   // x0l ready

  float hprev = 0.f;                    // wave0 lanes<32: own-col h
  for (int s = 0; s < 512; ++s) {
    float hpoll = 0.f;
    if (s > 0) {
      // Poll ONLY this wave's k-slice: float 64*wave + lane of slot s&1.
      const float base = ((s >> 1) & 1) ? 8.f : 2.f;
      const float* hp = hbuf + ((s & 1) << 9) + 64 * wave + lane;
      float v; bool ok;
      do {
        v = f32_ld(hp);
        ok = __builtin_fabsf(v - base) < 1.25f;
      } while (!__all(ok));
      hpoll = v - base;
    }
    // Intra-wave redistribution: lane l needs h[K0+j] held by lane (l&32)+j.
    float a0 = 0.f, a1 = 0.f, a2 = 0.f;
#pragma unroll
    for (int j = 0; j < 32; ++j) {
      const float hk = __shfl(hpoll, (lane & 32) + j);
      a0 = fmaf(hk, w3[0][j], a0);
      a1 = fmaf(hk, w3[1][j], a1);
      a2 = fmaf(hk, w3[2][j], a2);
    }
    // Combine the two k-halves (lanes l and l^32 share a column).
    a0 += __shfl_xor(a0, 32);
    a1 += __shfl_xor(a1, 32);
    a2 += __shfl_xor(a2, 32);
    const int par = s & 1;
    if (lane < 32) {
      red[par][wave][0][lane] = a0;
      red[par][wave][1][lane] = a1;
      red[par][wave][2][lane] = a2;
    }
    __syncthreads();   // the ONLY per-step barrier
    if (tid < 32) {
      float d0 = 0.f, d1 = 0.f, d2 = 0.f;
#pragma unroll
      for (int ww = 0; ww < 8; ++ww) {
        d0 += red[par][ww][0][tid];
        d1 += red[par][ww][1][tid];
        d2 += red[par][ww][2][tid];
      }
      const float xt = x0l[s];
      const float z  = sigm(fmaf(xt, k0z, biz) + d0 + brz);
      const float r  = sigm(fmaf(xt, k0r, bir) + d1 + brr);
      const float hh = tanh_f(fmaf(xt, k0n, bin_) + r * (d2 + brn));
      const float hnew = z * hprev + (1.f - z) * hh;
      hprev = hnew;
      if (s < 511) {
        const float nb = (((s + 1) >> 1) & 1) ? 8.f : 2.f;
        f32_st(&hbuf[(((s + 1) & 1) << 9) + 32 * g + tid], hnew + nb);
      } else {
        lout[32 * g + tid] = hnew;   // y0 for the chain kernel
      }
    }
  }
}

// ---- KRC2: chain phase, 64 WGs (proven in R6's passing run) ----------------
__global__ __launch_bounds__(512, 1) void krc2_kernel(
    const float* __restrict__ kc, const float* __restrict__ bc,
    const float* __restrict__ h1, const float* __restrict__ gh2,
    const float* __restrict__ y0, float* __restrict__ lout, float* part) {
  __shared__ float ccon[15 * 56];   // per ci: bi_d[24], g2_d[24], h1v[8]
  __shared__ float dots[24];
  __shared__ float yl[8];
  const int tid  = threadIdx.x;
  const int g    = blockIdx.x;
  const int wave = tid >> 6, lane = tid & 63;
  const int col8 = g * 8;

  for (int idx = tid; idx < 15 * 56; idx += 512) {
    const int ci = idx / 56, r = idx - ci * 56;
    float v;
    if (r < 24)      v = bc[(size_t)ci * 3072 + (r >> 3) * 512 + col8 + (r & 7)];
    else if (r < 48) v = gh2[ci * 1536 + ((r - 24) >> 3) * 512 + col8 + ((r - 24) & 7)];
    else             v = h1[ci * 512 + col8 + (r - 48)];
    ccon[idx] = v;
  }
  if (tid < 8) yl[tid] = y0[col8 + tid];
  const int col = col8 + tid;   // valid for tid<8
  __syncthreads();

  for (int ci = 0; ci < 15; ++ci) {
    float y[8];
#pragma unroll
    for (int j = 0; j < 8; ++j) y[j] = yl[j];
    const float* kbase = kc + (size_t)ci * 786432 + (size_t)col8 * 1536 + tid;
    float a0 = 0.f, a1 = 0.f, a2 = 0.f;
#pragma unroll
    for (int j = 0; j < 8; ++j) {
      const float* row = kbase + (size_t)j * 1536;
      a0 = fmaf(y[j], row[0],    a0);
      a1 = fmaf(y[j], row[512],  a1);
      a2 = fmaf(y[j], row[1024], a2);
    }
    const float pb = ((ci >> 1) & 1) ? 16.f : 4.f;   // |partial| <= ~1.5 << 3
    float* pbuf = part + (size_t)(ci & 1) * (1536 * 64);
    f32_st(&pbuf[(size_t)tid * 64 + g],          a0 + pb);
    f32_st(&pbuf[(size_t)(tid + 512) * 64 + g],  a1 + pb);
    f32_st(&pbuf[(size_t)(tid + 1024) * 64 + g], a2 + pb);

    const float* r0 = &pbuf[(size_t)(col8 + wave) * 64 + lane];
    const float* r1 = &pbuf[(size_t)(512 + col8 + wave) * 64 + lane];
    const float* r2 = &pbuf[(size_t)(1024 + col8 + wave) * 64 + lane];
    float v0, v1, v2;
    bool ok;
    do {
      v0 = f32_ld(r0); v1 = f32_ld(r1); v2 = f32_ld(r2);
      ok = (__builtin_fabsf(v0 - pb) < 3.f) &&
           (__builtin_fabsf(v1 - pb) < 3.f) &&
           (__builtin_fabsf(v2 - pb) < 3.f);
    } while (!__all(ok));
    v0 -= pb; v1 -= pb; v2 -= pb;
    v0 += __shfl_xor(v0, 1);  v0 += __shfl_xor(v0, 2);  v0 += __shfl_xor(v0, 4);
    v0 += __shfl_xor(v0, 8);  v0 += __shfl_xor(v0, 16); v0 += __shfl_xor(v0, 32);
    v1 += __shfl_xor(v1, 1);  v1 += __shfl_xor(v1, 2);  v1 += __shfl_xor(v1, 4);
    v1 += __shfl_xor(v1, 8);  v1 += __shfl_xor(v1, 16); v1 += __shfl_xor(v1, 32);
    v2 += __shfl_xor(v2, 1);  v2 += __shfl_xor(v2, 2);  v2 += __shfl_xor(v2, 4);
    v2 += __shfl_xor(v2, 8);  v2 += __shfl_xor(v2, 16); v2 += __shfl_xor(v2, 32);
    if (lane == 0) { dots[wave] = v0; dots[8 + wave] = v1; dots[16 + wave] = v2; }
    __syncthreads();
    if (tid < 8) {
      const float* cc = &ccon[ci * 56];
      const float dz = dots[tid], dr = dots[8 + tid], dn = dots[16 + tid];
      const float z  = sigm(dz + cc[tid]      + cc[24 + tid]);
      const float r  = sigm(dr + cc[8 + tid]  + cc[32 + tid]);
      const float hh = tanh_f(dn + cc[16 + tid] + r * cc[40 + tid]);
      const float hnew = z * cc[48 + tid] + (1.f - z) * hh;
      lout[(ci + 1) * 512 + col] = hnew;
      yl[tid] = hnew;
    }
    __syncthreads();   // yl visible for next step's partials
  }
}

// ---------------------------------------------------------------------------
// d_ws layout (floats):
//   hbuf:  3 * 1024                      @ 0
//   part:  3 * 196608                    @ 3072    (ends 592896)
//   h1:    15*512                        @ 592896
//   gh2:   15*1536                       @ 600576
//   lay1:  8192                          @ 623616
//   lay2:  8192                          @ 631808   (total 640000 fl = 2.56 MB)
// [0,592896) zeroed per launch: 0 is outside every poll window, so neither
// first-run garbage nor a previous replay's encoded values can alias.
// ---------------------------------------------------------------------------
extern "C" void kernel_launch(void* const* d_in, const int* in_sizes, int n_in,
                              void* d_out, int out_size, void* d_ws, size_t ws_size,
                              hipStream_t stream) {
  (void)in_sizes; (void)n_in; (void)out_size; (void)ws_size;
  const float* x = (const float*)d_in[0];
  float* F    = (float*)d_ws;
  float* hbuf = F;                 // 3*1024
  float* part = F + 3072;          // 3*196608
  float* h1   = F + 592896;        // 7680
  float* gh2  = F + 600576;        // 23040
  float* lay1 = F + 623616;        // 8192
  float* lay2 = F + 631808;        // 8192
  float* outf = (float*)d_out;

  hipMemsetAsync(F, 0, 592896 * sizeof(float), stream);

  const float* lin = x;
  float* louts[3] = {lay1, lay2, outf};
  for (int l = 0; l < 3; ++l) {
    const float* k0  = (const float*)d_in[1 + 6 * l + 0];
    const float* rk0 = (const float*)d_in[1 + 6 * l + 1];
    const float* b0  = (const float*)d_in[1 + 6 * l + 2];
    const float* kc  = (const float*)d_in[1 + 6 * l + 3];
    const float* rkc = (const float*)d_in[1 + 6 * l + 4];
    const float* bc  = (const float*)d_in[1 + 6 * l + 5];
    ka1_kernel<<<240, 256, 0, stream>>>(lin, kc, bc, h1);
    ka2_kernel<<<360, 256, 0, stream>>>(h1, rkc, bc, gh2);
    krr_kernel<<<NWGR, 512, 0, stream>>>(lin, k0, rk0, b0, louts[l],
                                         hbuf + l * 1024);
    krc2_kernel<<<NWG, 512, 0, stream>>>(kc, bc, h1, gh2, louts[l], louts[l],
                                         part + (size_t)l * 196608);
    lin = louts[l];
  }
}